// Round 14
// baseline (111.221 us; speedup 1.0000x reference)
//
#include <hip/hip_runtime.h>
#include <hip/hip_bf16.h>

typedef __attribute__((ext_vector_type(8))) short bf16x8;
typedef __attribute__((ext_vector_type(4))) float f32x4;

#define N_TOKENS 16384
#define DIM 4096
#define TOKB 32            // tokens per block
#define BK 128             // K floats per staged tile
#define NIT (DIM / BK)     // 32 iterations (16 super-iterations)
#define NBUF 4
#define BUF_F (TOKB * BK)  // 4096 floats (16 KB) per buffer
#define N_EXP 64

// d_out layout (all float32):
//   [0, 32768)              topk_experts as float  [token][2]
//   [32768, 65536)          combine_weight         [token][2]
//   [65536, 65536+1048576)  scores                 [token][64]
//   [1114112]               load_balance_loss
//   [1114113]               z_loss
#define OFF_W   (N_TOKENS * 2)
#define OFF_S   (N_TOKENS * 4)
#define OFF_LBL (N_TOKENS * 4 + N_TOKENS * N_EXP)
#define OFF_Z   (OFF_LBL + 1)

// ws layout (floats): [0..63] me partials, [64..127] ce partials, [128] z partial,
// [512 ..) w_hi as ushort[64*4096] (512 KB), then w_lo as ushort[64*4096] (512 KB)
#define WS_WHI_F 512
#define WS_WLO_F (512 + (N_EXP * DIM) / 2)

typedef const __attribute__((address_space(1))) void GV;
typedef __attribute__((address_space(3))) void LV;

// ---- cheap truncation split: f = hi + r exactly at 8 mantissa bits; lo = trunc(r).
__device__ __forceinline__ unsigned int pkhi(float a, float b) {
  // dst = [hi16(b) : hi16(a)]  (element 0 = a)
  return __builtin_amdgcn_perm(__float_as_uint(b), __float_as_uint(a), 0x07060302u);
}
__device__ __forceinline__ float resid(float f) {
  return f - __uint_as_float(__float_as_uint(f) & 0xFFFF0000u);
}
__device__ __forceinline__ void tsplit8(const f32x4 p0, const f32x4 p1,
                                        bf16x8& hi, bf16x8& lo) {
  uint4 H = make_uint4(pkhi(p0[0], p0[1]), pkhi(p0[2], p0[3]),
                       pkhi(p1[0], p1[1]), pkhi(p1[2], p1[3]));
  float r0 = resid(p0[0]), r1 = resid(p0[1]), r2 = resid(p0[2]), r3 = resid(p0[3]);
  float r4 = resid(p1[0]), r5 = resid(p1[1]), r6 = resid(p1[2]), r7 = resid(p1[3]);
  uint4 L = make_uint4(pkhi(r0, r1), pkhi(r2, r3), pkhi(r4, r5), pkhi(r6, r7));
  hi = __builtin_bit_cast(bf16x8, H);
  lo = __builtin_bit_cast(bf16x8, L);
}

// pre-pass: w fp32 -> separate bf16 hi / lo planes (1 MB total, ~3 us); RNE here
__global__ __launch_bounds__(256) void split_w_kernel(
    const float* __restrict__ w,
    unsigned short* __restrict__ whi, unsigned short* __restrict__ wlo)
{
  const int i = blockIdx.x * 256 + threadIdx.x;  // 0 .. 64*4096-1
  float f = w[i];
  unsigned short h = __builtin_bit_cast(unsigned short, __float2bfloat16(f));
  float hf = __uint_as_float(((unsigned)h) << 16);
  unsigned short l = __builtin_bit_cast(unsigned short, __float2bfloat16(f - hf));
  whi[i] = h;
  wlo[i] = l;
}

__global__ __launch_bounds__(512, 4) void router_kernel(
    const float* __restrict__ x,
    const unsigned short* __restrict__ whi, const unsigned short* __restrict__ wlo,
    float* __restrict__ out, float* __restrict__ ws)
{
  // 4 linear fp32 x-tile buffers [32][128] (64 KB); reused as logits in epilogue.
  // Content is source-swizzled at 16B granularity: LDS[row][u] = x[row][u ^ (row&7)]
  __shared__ __align__(16) float smem[NBUF * BUF_F];

  const int tid  = threadIdx.x;
  const int lane = tid & 63;
  const int wv   = __builtin_amdgcn_readfirstlane(tid >> 6);  // 0..7, wave-uniform
  const int q    = wv & 1;     // expert half (32 experts)
  const int kq   = wv >> 1;    // k-slice: 0..3 (32 floats each within BK)
  const int half = lane >> 4;  // 0..3
  const int r15  = lane & 15;
  const int tok0 = blockIdx.x * TOKB;

  // staging: wave wv covers rows wv*4..+3 of the [32][128] tile
  const int row0 = wv * 4 + (lane >> 5);
  const int row1 = row0 + 2;
  const int sU   = lane & 31;
  const float* g0 = x + (size_t)(tok0 + row0) * DIM + ((sU ^ (row0 & 7)) << 2);
  const float* g1 = x + (size_t)(tok0 + row1) * DIM + ((sU ^ (row1 & 7)) << 2);
  float* const ldst = smem + wv * 512;  // wave-uniform

#define STAGE(buf, it_) do {                                                  \
    const float* s0_ = g0 + (size_t)(it_) * BK;                               \
    const float* s1_ = g1 + (size_t)(it_) * BK;                               \
    float* d_ = ldst + (buf) * BUF_F;                                         \
    __builtin_amdgcn_global_load_lds((GV*)s0_, (LV*)d_,       16, 0, 0);      \
    __builtin_amdgcn_global_load_lds((GV*)s1_, (LV*)(d_+256), 16, 0, 0);      \
  } while (0)

  // w fragment base: expert rows q*32 + n*16 + r15, k-offset kq*32 + half*8
  const unsigned short* wh0 = whi + (size_t)(q * 32 + r15) * DIM + kq * 32 + half * 8;
  const unsigned short* wl0 = wlo + (size_t)(q * 32 + r15) * DIM + kq * 32 + half * 8;

  f32x4 acc[2][2];
#pragma unroll
  for (int tt = 0; tt < 2; ++tt)
#pragma unroll
    for (int n = 0; n < 2; ++n) acc[tt][n] = (f32x4){0.f, 0.f, 0.f, 0.f};

  // ---- prologue: FIFO = stage0(2), stage1(2) ----
  STAGE(0, 0);
  STAGE(1, 1);

  for (int s = 0; s < NIT / 2; ++s) {
    const int it0 = 2 * s, it1 = 2 * s + 1;

    // --- 8 w-loads for it0 and it1 (oldest ops in this slot) ---
    bf16x8 bh0[2], bl0[2], bh1[2], bl1[2];
#pragma unroll
    for (int n = 0; n < 2; ++n) {
      const size_t nd = (size_t)n * 16 * DIM;
      bh0[n] = *(const bf16x8*)(wh0 + (size_t)it0 * BK + nd);
      bl0[n] = *(const bf16x8*)(wl0 + (size_t)it0 * BK + nd);
      bh1[n] = *(const bf16x8*)(wh0 + (size_t)it1 * BK + nd);
      bl1[n] = *(const bf16x8*)(wl0 + (size_t)it1 * BK + nd);
    }

    // retire only up to the PREVIOUS slot's 4 stage-gll (the buffers we now read);
    // this slot's 8 w-loads stay in flight.
    asm volatile("s_waitcnt vmcnt(8)" ::: "memory");
    __builtin_amdgcn_s_barrier();

    // --- stages for it0+2 / it1+2, issued AFTER the barrier (no WAR race) ---
    STAGE((it0 + 2) & 3, (it0 + 2 < NIT) ? it0 + 2 : NIT - 1);
    STAGE((it1 + 2) & 3, (it1 + 2 < NIT) ? it1 + 2 : NIT - 1);

    // --- compute it0 then it1 (compiler auto-wait for w = vmcnt(4): stages fly on) ---
#pragma unroll
    for (int ii = 0; ii < 2; ++ii) {
      const int itc = ii ? it1 : it0;
      const float* bufp = smem + (itc & 3) * BUF_F;
#pragma unroll
      for (int tt = 0; tt < 2; ++tt) {
        const int rowA = tt * 16 + r15;
        const int g    = r15 & 7;
        const float* rp = bufp + rowA * BK;
        const int u0 = (kq * 8 + half * 2) ^ g;
        const int u1 = (kq * 8 + half * 2 + 1) ^ g;
        f32x4 p0 = *(const f32x4*)(rp + (u0 << 2));
        f32x4 p1 = *(const f32x4*)(rp + (u1 << 2));
        bf16x8 ah, al;
        tsplit8(p0, p1, ah, al);
#pragma unroll
        for (int n = 0; n < 2; ++n) {
          const bf16x8 bh = ii ? bh1[n] : bh0[n];
          const bf16x8 bl = ii ? bl1[n] : bl0[n];
          acc[tt][n] = __builtin_amdgcn_mfma_f32_16x16x32_bf16(ah, bh, acc[tt][n], 0, 0, 0);
          acc[tt][n] = __builtin_amdgcn_mfma_f32_16x16x32_bf16(al, bh, acc[tt][n], 0, 0, 0);
          acc[tt][n] = __builtin_amdgcn_mfma_f32_16x16x32_bf16(ah, bl, acc[tt][n], 0, 0, 0);
        }
      }
    }
  }

  // drain all outstanding gll writes (incl. clamped tail stages) before smem reuse
  asm volatile("s_waitcnt vmcnt(0)" ::: "memory");
  __syncthreads();

  // ---- epilogue: reuse smem as 4 kq-partial logit buffers [32][65] ----
  float* lb = smem;
  {
    float* dst = lb + kq * (TOKB * 65);
#pragma unroll
    for (int tt = 0; tt < 2; ++tt) {
#pragma unroll
      for (int n = 0; n < 2; ++n) {
#pragma unroll
        for (int r = 0; r < 4; ++r) {
          dst[(tt * 16 + half * 4 + r) * 65 + q * 32 + n * 16 + r15] = acc[tt][n][r];
        }
      }
    }
  }
  __syncthreads();

  // combine the four kq partials
  for (int i = tid; i < TOKB * 64; i += 512) {
    const int t = i >> 6, e = i & 63;
    lb[t * 65 + e] += lb[2080 + t * 65 + e] + lb[4160 + t * 65 + e] + lb[6240 + t * 65 + e];
  }
  __syncthreads();

  if (wv == 0 && lane < TOKB) {
    // lane owns one token: full softmax + top-2 + z-loss
    const int token = tok0 + lane;
    float v[64];
#pragma unroll
    for (int e = 0; e < 64; ++e) v[e] = lb[lane * 65 + e];
    float m = v[0];
#pragma unroll
    for (int e = 1; e < 64; ++e) m = fmaxf(m, v[e]);
    float sum = 0.f;
#pragma unroll
    for (int e = 0; e < 64; ++e) { v[e] = expf(v[e] - m); sum += v[e]; }
    const float inv = 1.0f / sum;
    float m1 = -1.f, m2 = -1.f;
    int   i1 = 0,    i2 = 0;
#pragma unroll
    for (int e = 0; e < 64; ++e) {
      float sc = v[e] * inv;
      lb[lane * 65 + e] = sc;
      if (sc > m1)      { m2 = m1; i2 = i1; m1 = sc; i1 = e; }
      else if (sc > m2) { m2 = sc; i2 = e; }
    }
    out[2 * token]         = (float)i1;
    out[2 * token + 1]     = (float)i2;
    out[OFF_W + 2 * token]     = m1;
    out[OFF_W + 2 * token + 1] = m2;

    float lse = m + logf(sum);
    float z = lse * lse;
#pragma unroll
    for (int off = 16; off > 0; off >>= 1) z += __shfl_down(z, off);
    if (lane == 0) atomicAdd(ws + 128, z);
  }
  __syncthreads();

  // coalesced scores store for this block's 32 tokens
  float* outS = out + OFF_S + (size_t)blockIdx.x * TOKB * 64;
  for (int i = tid; i < TOKB * 64; i += 512) {
    outS[i] = lb[(i >> 6) * 65 + (i & 63)];
  }

  // per-expert partial me / ce for this block's tokens (expert = lane)
  if (wv == 0) {
    float sm = 0.f, cn = 0.f;
#pragma unroll
    for (int t = 0; t < TOKB; ++t) {
      float sc = lb[t * 65 + lane];
      sm += sc;
      cn += (sc > 0.f) ? 1.f : 0.f;
    }
    atomicAdd(ws + lane, sm);
    atomicAdd(ws + 64 + lane, cn);
  }
#undef STAGE
}

__global__ void finalize_kernel(const float* __restrict__ ws, float* __restrict__ out) {
  const int l = threadIdx.x;  // 64 threads
  const float invT = 1.0f / (float)N_TOKENS;
  float me = ws[l] * invT;
  float ce = ws[64 + l] * invT;
  float p = me * ce;
#pragma unroll
  for (int off = 32; off > 0; off >>= 1) p += __shfl_down(p, off);
  if (l == 0) {
    out[OFF_LBL] = p * (float)N_EXP;
    out[OFF_Z]   = ws[128] * invT;
  }
}

extern "C" void kernel_launch(void* const* d_in, const int* in_sizes, int n_in,
                              void* d_out, int out_size, void* d_ws, size_t ws_size,
                              hipStream_t stream) {
  const float* x = (const float*)d_in[0];
  const float* w = (const float*)d_in[1];
  float* out = (float*)d_out;
  float* ws  = (float*)d_ws;
  unsigned short* whi = (unsigned short*)(ws + WS_WHI_F);
  unsigned short* wlo = (unsigned short*)(ws + WS_WLO_F);

  (void)hipMemsetAsync(d_ws, 0, 129 * sizeof(float), stream);
  split_w_kernel<<<(N_EXP * DIM) / 256, 256, 0, stream>>>(w, whi, wlo);
  router_kernel<<<N_TOKENS / TOKB, 512, 0, stream>>>(x, whi, wlo, out, ws);
  finalize_kernel<<<1, 64, 0, stream>>>(ws, out);
}